// Round 5
// baseline (250.901 us; speedup 1.0000x reference)
//
#include <hip/hip_runtime.h>
#include <cstdint>
#include <cstddef>

typedef unsigned short ushort_t;
typedef __attribute__((ext_vector_type(4))) float f32x4;
typedef __attribute__((ext_vector_type(16))) float f32x16;
typedef __attribute__((ext_vector_type(8))) short short8;
typedef __attribute__((ext_vector_type(4))) float float4_t;
typedef __attribute__((ext_vector_type(4))) unsigned short ushort4_t;
typedef __attribute__((ext_vector_type(2))) unsigned int uint2v;

#define KD 2048     // inner dim of both GEMMs
#define TT 2048     // sequence length T
#define NH 32       // heads
#define NG 8        // kv groups

__device__ __forceinline__ ushort_t f2bf(float f) {
  union { float f; uint32_t u; } cv; cv.f = f;
  uint32_t u = cv.u;
  return (ushort_t)((u + 0x7FFFu + ((u >> 16) & 1u)) >> 16);
}

__device__ __forceinline__ uint32_t cvtpk(float a, float b) {
  uint32_t r;
  asm("v_cvt_pk_bf16_f32 %0, %1, %2" : "=v"(r) : "v"(a), "v"(b));
  return r;
}

__device__ __forceinline__ float exp2fast(float x) {
  float r;
  asm("v_exp_f32 %0, %1" : "=v"(r) : "v"(x));
  return r;
}

__device__ __forceinline__ void gload_lds16(const void* g, void* l) {
  __builtin_amdgcn_global_load_lds(
      (const __attribute__((address_space(1))) unsigned int*)g,
      (__attribute__((address_space(3))) unsigned int*)l, 16, 0, 0);
}

// ---------------- x f32 -> bf16 ----------------
__global__ __launch_bounds__(256) void cvt_x_kernel(const float* __restrict__ src,
                                                    ushort_t* __restrict__ dst) {
  int i = (blockIdx.x * 256 + threadIdx.x) * 4;
  float4_t v = *(const float4_t*)(src + i);
  ushort4_t o;
  o[0] = f2bf(v[0]); o[1] = f2bf(v[1]); o[2] = f2bf(v[2]); o[3] = f2bf(v[3]);
  *(ushort4_t*)(dst + i) = o;
}

// ---------------- W f32 [K][Nc] -> bf16 [Nc][K] (transposed) ----------------
__global__ __launch_bounds__(256) void cvt_transpose_kernel(const float* __restrict__ src,
                                                            ushort_t* __restrict__ dst,
                                                            int Nc) {
  __shared__ float tile[32][33];
  int tx = threadIdx.x, ty = threadIdx.y;
  int c0 = blockIdx.x * 32, r0 = blockIdx.y * 32;
#pragma unroll
  for (int i = 0; i < 4; i++)
    tile[ty + i * 8][tx] = src[(size_t)(r0 + ty + i * 8) * Nc + c0 + tx];
  __syncthreads();
#pragma unroll
  for (int i = 0; i < 4; i++)
    dst[(size_t)(c0 + ty + i * 8) * KD + r0 + tx] = f2bf(tile[tx][ty + i * 8]);
}

// ---------------- v [b][g][t][d] -> vt [b][g][d][t] ----------------
__global__ __launch_bounds__(256) void vtrans_kernel(const ushort_t* __restrict__ v,
                                                     ushort_t* __restrict__ vt) {
  __shared__ ushort_t tile[64][72];
  const int bg = blockIdx.y;
  const int t0 = blockIdx.x * 64;
  const ushort_t* src = v + ((size_t)bg * TT + t0) * 64;
#pragma unroll
  for (int i = 0; i < 2; ++i) {
    int p = i * 256 + threadIdx.x;
    int r = p >> 3, c = (p & 7) * 8;
    *(short8*)&tile[r][c] = *(const short8*)(src + r * 64 + c);
  }
  __syncthreads();
  ushort_t* dst = vt + (size_t)bg * 64 * TT + t0;
#pragma unroll
  for (int i = 0; i < 2; ++i) {
    int p = i * 256 + threadIdx.x;
    int d = p >> 3, c = (p & 7) * 8;
    short8 o;
#pragma unroll
    for (int j = 0; j < 8; ++j) o[j] = tile[c + j][d];
    *(short8*)(dst + (size_t)d * TT + c) = o;
  }
}

// ---------------- outF += p1 ----------------
__global__ __launch_bounds__(256) void addp_kernel(float* __restrict__ out,
                                                   const float* __restrict__ p1) {
  int i = (blockIdx.x * 256 + threadIdx.x) * 4;
  float4_t a = *(const float4_t*)(out + i);
  float4_t b = *(const float4_t*)(p1 + i);
  a[0] += b[0]; a[1] += b[1]; a[2] += b[2]; a[3] += b[3];
  *(float4_t*)(out + i) = a;
}

// ---------------- GEMM 2-phase counted-vmcnt: C = A[M][K] * Bt[N][K]^T -----
// 128x128 tile, BK=64, 256 threads = 4 waves (2x2), double-buffered LDS.
// Per tile: issue stage(t+1) -> vmcnt(8) (own tile-t loads) -> barrier ->
// ds_read+MFMA (compiler-scheduled) -> barrier. Loads stay 1 tile in flight.
// MODE 0: QKV + RoPE epilogue. MODE 1: split-K proj (blockIdx.z = K-half).
template <int MODE>
__global__ __launch_bounds__(256) void gemm2_kernel(
    const ushort_t* __restrict__ A, const ushort_t* __restrict__ Bt,
    const float* __restrict__ cosT, const float* __restrict__ sinT,
    ushort_t* __restrict__ q_ws, ushort_t* __restrict__ k_ws,
    ushort_t* __restrict__ v_ws, float* __restrict__ kcache,
    float* __restrict__ vcache, float* __restrict__ outF,
    float* __restrict__ outP1) {
  __shared__ ushort_t sA[2][128 * 64];
  __shared__ ushort_t sB[2][128 * 64];
  const int tid = threadIdx.x;
  const int lane = tid & 63;
  const int w = tid >> 6;
  const int wr = w >> 1, wc = w & 1;
  const int rowBase = blockIdx.y * 128;
  const int colBase = blockIdx.x * 128;
  const int kBase = (MODE == 1) ? blockIdx.z * (KD / 2) : 0;
  const int NT = (MODE == 1) ? (KD / 2) / 64 : KD / 64;

  // staging: chunk p=(it*256+tid) -> row p>>3; phys slot p&7 holds logical
  // chunk (p&7)^(row&7) (source pre-swizzled, LDS dest linear).
  const ushort_t* aSrc[4];
  const ushort_t* bSrc[4];
  int ldsOff[4];
#pragma unroll
  for (int it = 0; it < 4; ++it) {
    int p = it * 256 + tid;
    int r = p >> 3, c = (p & 7) ^ (r & 7);
    aSrc[it] = A + (size_t)(rowBase + r) * KD + kBase + c * 8;
    bSrc[it] = Bt + (size_t)(colBase + r) * KD + kBase + c * 8;
    ldsOff[it] = (it * 256 + (tid & ~63)) * 8;
  }

  auto stage = [&](int bb, int koff) {
#pragma unroll
    for (int it = 0; it < 4; ++it) gload_lds16(aSrc[it] + koff, &sA[bb][ldsOff[it]]);
#pragma unroll
    for (int it = 0; it < 4; ++it) gload_lds16(bSrc[it] + koff, &sB[bb][ldsOff[it]]);
  };

  f32x4 acc[4][4];
#pragma unroll
  for (int i = 0; i < 4; i++)
#pragma unroll
    for (int j = 0; j < 4; j++) acc[i][j] = f32x4{0.f, 0.f, 0.f, 0.f};

  stage(0, 0);

  for (int t = 0; t < NT; ++t) {
    const int buf = t & 1;
    if (t + 1 < NT) {
      stage(buf ^ 1, (t + 1) * 64);
      asm volatile("s_waitcnt vmcnt(8)" ::: "memory");
    } else {
      asm volatile("s_waitcnt vmcnt(0)" ::: "memory");
    }
    __builtin_amdgcn_s_barrier();

#pragma unroll
    for (int ks = 0; ks < 2; ++ks) {
      short8 af[4], bfr[4];
#pragma unroll
      for (int mi = 0; mi < 4; ++mi) {
        int r = wr * 64 + mi * 16 + (lane & 15);
        af[mi] = *(const short8*)(&sA[buf][r * 64 + (((ks * 4 + (lane >> 4)) ^ (r & 7)) * 8)]);
      }
#pragma unroll
      for (int ni = 0; ni < 4; ++ni) {
        int n = wc * 64 + ni * 16 + (lane & 15);
        bfr[ni] = *(const short8*)(&sB[buf][n * 64 + (((ks * 4 + (lane >> 4)) ^ (n & 7)) * 8)]);
      }
      __builtin_amdgcn_s_setprio(1);
#pragma unroll
      for (int mi = 0; mi < 4; ++mi)
#pragma unroll
        for (int ni = 0; ni < 4; ++ni)
          acc[mi][ni] = __builtin_amdgcn_mfma_f32_16x16x32_bf16(af[mi], bfr[ni],
                                                                acc[mi][ni], 0, 0, 0);
      __builtin_amdgcn_s_setprio(0);
    }
    __builtin_amdgcn_s_barrier();
  }

  // ---- epilogue: C/D layout col=lane&15, row=(lane>>4)*4+j ----
#pragma unroll
  for (int mi = 0; mi < 4; ++mi)
#pragma unroll
    for (int ni = 0; ni < 4; ++ni) {
      int cg = colBase + wc * 64 + ni * 16 + (lane & 15);
      int rg0 = rowBase + wr * 64 + mi * 16 + ((lane >> 4) * 4);
      f32x4 v4 = acc[mi][ni];
#pragma unroll
      for (int j = 0; j < 4; ++j) {
        float v = v4[j];
        float pv = __shfl_xor(v, 1);
        int row = rg0 + j;
        if constexpr (MODE == 0) {
          int bb = row >> 11, tq = row & (TT - 1);
          int d = cg & 63, i2 = d >> 1;
          if (cg < 2048) {  // q (scale folds 1/8 and log2(e) for exp2 softmax)
            float cc = cosT[tq * 32 + i2], ss = sinT[tq * 32 + i2];
            float out = (d & 1) ? (pv * ss + v * cc) : (v * cc - pv * ss);
            int hh = cg >> 6;
            q_ws[(((size_t)(bb * NH + hh)) * TT + tq) * 64 + d] = f2bf(out * 0.18033688f);
          } else if (cg < 2560) {  // k (roped)
            float cc = cosT[tq * 32 + i2], ss = sinT[tq * 32 + i2];
            float out = (d & 1) ? (pv * ss + v * cc) : (v * cc - pv * ss);
            int gg = (cg - 2048) >> 6;
            kcache[(((size_t)(bb * TT + tq)) * NG + gg) * 64 + d] = out;
            k_ws[(((size_t)(bb * NG + gg)) * TT + tq) * 64 + d] = f2bf(out);
          } else {  // v (row-major now; transpose kernel builds vt)
            int gg = (cg - 2560) >> 6;
            vcache[(((size_t)(bb * TT + tq)) * NG + gg) * 64 + d] = v;
            v_ws[(((size_t)(bb * NG + gg)) * TT + tq) * 64 + d] = f2bf(v);
          }
        } else {
          float* dst = blockIdx.z ? outP1 : outF;
          dst[(size_t)row * 2048 + cg] = v;
        }
      }
    }
}

// ---------------- flash attention: swapped 32x32 MFMA, in-register softmax
#define PACK(SV, E, OUT)                                        \
  {                                                             \
    uint32_t A0 = cvtpk(SV[8 * E + 0], SV[8 * E + 1]);          \
    uint32_t A1 = cvtpk(SV[8 * E + 2], SV[8 * E + 3]);          \
    uint32_t B0 = cvtpk(SV[8 * E + 4], SV[8 * E + 5]);          \
    uint32_t B1 = cvtpk(SV[8 * E + 6], SV[8 * E + 7]);          \
    asm("v_permlane32_swap_b32 %0, %1" : "+v"(A0), "+v"(B0));   \
    asm("v_permlane32_swap_b32 %0, %1" : "+v"(A1), "+v"(B1));   \
    union { uint32_t u[4]; short8 s8; } UU;                     \
    UU.u[0] = A0; UU.u[1] = A1; UU.u[2] = B0; UU.u[3] = B1;     \
    OUT = UU.s8;                                                \
  }

__global__ __launch_bounds__(256, 4) void attn_kernel(const ushort_t* __restrict__ qw,
                                                      const ushort_t* __restrict__ kw,
                                                      const ushort_t* __restrict__ vtw,
                                                      ushort_t* __restrict__ attn) {
  __shared__ ushort_t sK[2][4096];   // [64 keys][64 d], chunk-swizzled
  __shared__ ushort_t sVT[2][4096];  // [64 d][64 keys], chunk-swizzled
  const int tid = threadIdx.x;
  const int lane = tid & 63;
  const int w = tid >> 6;
  const int hi = lane >> 5;
  const int col = lane & 31;
  const int bid = blockIdx.x;
  const int jj = bid & 63;
  const int rep = jj >> 4;
  const int bg = jj & 15;
  const int b = bg >> 3, g = bg & 7;
  const int h = g * 4 + rep;
  const int qt = 15 - (bid >> 6);
  const int q0w = qt * 128 + w * 32;
  const int qg = q0w + col;
  const int ntiles = 2 * qt + 2;

  const ushort_t* qbase = qw + ((size_t)(b * NH + h) * TT + qg) * 64;
  const ushort_t* kbase = kw + (size_t)(b * NG + g) * TT * 64;
  const ushort_t* vtbase = vtw + (size_t)(b * NG + g) * 64 * TT;

  short8 qf[4];
#pragma unroll
  for (int dsub = 0; dsub < 4; ++dsub)
    qf[dsub] = *(const short8*)(qbase + dsub * 16 + hi * 8);

  const int r0 = tid >> 3;
  const int cl = (tid & 7) ^ (r0 & 7);
  const ushort_t* kS0 = kbase + r0 * 64 + cl * 8;
  const ushort_t* kS1 = kbase + (r0 + 32) * 64 + cl * 8;
  const ushort_t* vS0 = vtbase + (size_t)r0 * TT + cl * 8;
  const ushort_t* vS1 = vtbase + (size_t)(r0 + 32) * TT + cl * 8;
  const int off0 = (tid & ~63) * 8;
  const int off1 = off0 + 2048;

  auto stage = [&](int bb, int k0) {
    gload_lds16(kS0 + (size_t)k0 * 64, &sK[bb][off0]);
    gload_lds16(kS1 + (size_t)k0 * 64, &sK[bb][off1]);
    gload_lds16(vS0 + k0, &sVT[bb][off0]);
    gload_lds16(vS1 + k0, &sVT[bb][off1]);
  };

  f32x16 o0 = {};
  f32x16 o1 = {};
  float m_run = -3.0e38f, l_run = 0.f;

  stage(0, 0);
  asm volatile("s_waitcnt vmcnt(0)" ::: "memory");
  __syncthreads();

  for (int kt = 0; kt < ntiles; ++kt) {
    const int k0 = kt * 64;
    const int buf = kt & 1;
    if (kt + 1 < ntiles) stage(buf ^ 1, k0 + 64);
    if (k0 <= q0w + 31) {
      const ushort_t* K = sK[buf];
      const ushort_t* V = sVT[buf];
      f32x16 s0 = {};
      f32x16 s1 = {};
#pragma unroll
      for (int dsub = 0; dsub < 4; ++dsub) {
        const int ch = dsub * 2 + hi;
        const int sw = ((ch ^ (col & 7)) * 8);
        short8 a0 = *(const short8*)(K + col * 64 + sw);
        short8 a1 = *(const short8*)(K + (32 + col) * 64 + sw);
        s0 = __builtin_amdgcn_mfma_f32_32x32x16_bf16(a0, qf[dsub], s0, 0, 0, 0);
        s1 = __builtin_amdgcn_mfma_f32_32x32x16_bf16(a1, qf[dsub], s1, 0, 0, 0);
      }
      if (k0 + 63 > q0w) {
#pragma unroll
        for (int r = 0; r < 16; ++r) {
          int key5 = (r & 3) + 8 * (r >> 2) + 4 * hi;
          if (k0 + key5 > qg) s0[r] = -3.0e38f;
          if (k0 + 32 + key5 > qg) s1[r] = -3.0e38f;
        }
      }
      float tm[16];
#pragma unroll
      for (int r = 0; r < 16; ++r) tm[r] = fmaxf(s0[r], s1[r]);
#pragma unroll
      for (int st = 8; st > 0; st >>= 1)
#pragma unroll
        for (int r = 0; r < 8; ++r)
          if (r < st) tm[r] = fmaxf(tm[r], tm[r + st]);
      float mt = fmaxf(tm[0], __shfl_xor(tm[0], 32));
      float mn = fmaxf(m_run, mt);
      float al = exp2fast(m_run - mn);
      m_run = mn;
      float ts[16];
#pragma unroll
      for (int r = 0; r < 16; ++r) {
        s0[r] = exp2fast(s0[r] - mn);
        s1[r] = exp2fast(s1[r] - mn);
        ts[r] = s0[r] + s1[r];
      }
#pragma unroll
      for (int st = 8; st > 0; st >>= 1)
#pragma unroll
        for (int r = 0; r < 8; ++r)
          if (r < st) ts[r] += ts[r + st];
      float rs = ts[0] + __shfl_xor(ts[0], 32);
      l_run = l_run * al + rs;
#pragma unroll
      for (int r = 0; r < 16; ++r) { o0[r] *= al; o1[r] *= al; }
      short8 pb;
      const int swz = (col & 7);
#define PVMM(KS)                                                            \
  {                                                                         \
    const int ch = KS * 2 + hi;                                             \
    const int so = ((ch ^ swz) * 8);                                        \
    short8 va = *(const short8*)(V + col * 64 + so);                        \
    short8 vb = *(const short8*)(V + (32 + col) * 64 + so);                 \
    o0 = __builtin_amdgcn_mfma_f32_32x32x16_bf16(va, pb, o0, 0, 0, 0);      \
    o1 = __builtin_amdgcn_mfma_f32_32x32x16_bf16(vb, pb, o1, 0, 0, 0);      \
  }
      PACK(s0, 0, pb); PVMM(0)
      PACK(s0, 1, pb); PVMM(1)
      PACK(s1, 0, pb); PVMM(2)
      PACK(s1, 1, pb); PVMM(3)
#undef PVMM
    }
    asm volatile("s_waitcnt vmcnt(0)" ::: "memory");
    __syncthreads();
  }

  const float inv = 1.f / l_run;
  ushort_t* obase = attn + ((size_t)b * TT + qg) * 2048 + h * 64;
#pragma unroll
  for (int g4 = 0; g4 < 4; ++g4) {
    int d = g4 * 8 + hi * 4;
    uint2v u;
    u[0] = cvtpk(o0[4 * g4 + 0] * inv, o0[4 * g4 + 1] * inv);
    u[1] = cvtpk(o0[4 * g4 + 2] * inv, o0[4 * g4 + 3] * inv);
    *(uint2v*)(obase + d) = u;
    uint2v u2;
    u2[0] = cvtpk(o1[4 * g4 + 0] * inv, o1[4 * g4 + 1] * inv);
    u2[1] = cvtpk(o1[4 * g4 + 2] * inv, o1[4 * g4 + 3] * inv);
    *(uint2v*)(obase + 32 + d) = u2;
  }
}

extern "C" void kernel_launch(void* const* d_in, const int* in_sizes, int n_in,
                              void* d_out, int out_size, void* d_ws, size_t ws_size,
                              hipStream_t stream) {
  (void)in_sizes; (void)n_in; (void)out_size; (void)ws_size;
  const float* x    = (const float*)d_in[0];
  const float* cosT = (const float*)d_in[1];
  const float* sinT = (const float*)d_in[2];
  const float* Wq   = (const float*)d_in[4];
  const float* Wk   = (const float*)d_in[5];
  const float* Wv   = (const float*)d_in[6];
  const float* Wo   = (const float*)d_in[7];

  float* outF   = (float*)d_out;
  float* kcache = outF + (size_t)8388608;             // B*T*C
  float* vcache = kcache + (size_t)2097152;           // B*T*G*D

  // ws layout (76 MiB total, unchanged footprint):
  //  [ 0,16M)  x_bf          (dead after QKV)    } p1 (32 MiB f32) overlays
  //  [16,28M)  wqkvT         (dead after QKV)    } [0,32M) during proj —
  //  [16,20M)    vt_ws       (dead after attn)   } everything there is dead
  //  [28,44M)  q_ws          (dead after attn)   }
  //  [44,48M)  k_ws          (dead after attn)
  //  [48,52M)  v_ws          (dead after vtrans/attn)
  //  [52,60M)  woT           (live thru proj)
  //  [60,76M)  attn_ws       (live thru proj)
  uint8_t* ws = (uint8_t*)d_ws;
  ushort_t* x_bf   = (ushort_t*)(ws);
  ushort_t* wqkvT  = (ushort_t*)(ws + 16777216);
  ushort_t* vt_ws  = (ushort_t*)(ws + 16777216);
  ushort_t* q_ws   = (ushort_t*)(ws + 29360128);
  ushort_t* k_ws   = (ushort_t*)(ws + 46137344);
  ushort_t* v_ws   = (ushort_t*)(ws + 50331648);
  ushort_t* woT    = (ushort_t*)(ws + 54525952);
  ushort_t* attn_ws= (ushort_t*)(ws + 62914560);
  float*    p1     = (float*)(ws);

  cvt_x_kernel<<<8192, 256, 0, stream>>>(x, x_bf);
  cvt_transpose_kernel<<<dim3(64, 64), dim3(32, 8), 0, stream>>>(Wq, wqkvT, 2048);
  cvt_transpose_kernel<<<dim3(16, 64), dim3(32, 8), 0, stream>>>(Wk, wqkvT + (size_t)2048 * KD, 512);
  cvt_transpose_kernel<<<dim3(16, 64), dim3(32, 8), 0, stream>>>(Wv, wqkvT + (size_t)2560 * KD, 512);
  cvt_transpose_kernel<<<dim3(64, 64), dim3(32, 8), 0, stream>>>(Wo, woT, 2048);

  gemm2_kernel<0><<<dim3(24, 32), 256, 0, stream>>>(x_bf, wqkvT, cosT, sinT, q_ws,
                                                    k_ws, v_ws, kcache, vcache,
                                                    nullptr, nullptr);
  vtrans_kernel<<<dim3(32, 16), 256, 0, stream>>>(v_ws, vt_ws);
  attn_kernel<<<1024, 256, 0, stream>>>(q_ws, k_ws, vt_ws, attn_ws);
  gemm2_kernel<1><<<dim3(16, 32, 2), 256, 0, stream>>>(attn_ws, woT, nullptr, nullptr,
                                                       nullptr, nullptr, nullptr,
                                                       nullptr, nullptr, outF, p1);
  addp_kernel<<<8192, 256, 0, stream>>>(outF, p1);
}

// Round 6
// 219.256 us; speedup vs baseline: 1.1443x; 1.1443x over previous
//
#include <hip/hip_runtime.h>
#include <cstdint>
#include <cstddef>

typedef unsigned short ushort_t;
typedef __attribute__((ext_vector_type(4))) float f32x4;
typedef __attribute__((ext_vector_type(16))) float f32x16;
typedef __attribute__((ext_vector_type(8))) short short8;
typedef __attribute__((ext_vector_type(4))) float float4_t;
typedef __attribute__((ext_vector_type(4))) unsigned short ushort4_t;
typedef __attribute__((ext_vector_type(2))) unsigned int uint2v;

#define KD 2048     // inner dim of both GEMMs
#define TT 2048     // sequence length T
#define NH 32       // heads
#define NG 8        // kv groups

__device__ __forceinline__ ushort_t f2bf(float f) {
  union { float f; uint32_t u; } cv; cv.f = f;
  uint32_t u = cv.u;
  return (ushort_t)((u + 0x7FFFu + ((u >> 16) & 1u)) >> 16);
}

__device__ __forceinline__ uint32_t cvtpk(float a, float b) {
  uint32_t r;
  asm("v_cvt_pk_bf16_f32 %0, %1, %2" : "=v"(r) : "v"(a), "v"(b));
  return r;
}

__device__ __forceinline__ float exp2fast(float x) {
  float r;
  asm("v_exp_f32 %0, %1" : "=v"(r) : "v"(x));
  return r;
}

__device__ __forceinline__ void gload_lds16(const void* g, void* l) {
  __builtin_amdgcn_global_load_lds(
      (const __attribute__((address_space(1))) unsigned int*)g,
      (__attribute__((address_space(3))) unsigned int*)l, 16, 0, 0);
}

// ---------------- x f32 -> bf16 ----------------
__global__ __launch_bounds__(256) void cvt_x_kernel(const float* __restrict__ src,
                                                    ushort_t* __restrict__ dst) {
  int i = (blockIdx.x * 256 + threadIdx.x) * 4;
  float4_t v = *(const float4_t*)(src + i);
  ushort4_t o;
  o[0] = f2bf(v[0]); o[1] = f2bf(v[1]); o[2] = f2bf(v[2]); o[3] = f2bf(v[3]);
  *(ushort4_t*)(dst + i) = o;
}

// ---------------- W f32 [K][Nc] -> bf16 [Nc][K] (transposed) ----------------
__global__ __launch_bounds__(256) void cvt_transpose_kernel(const float* __restrict__ src,
                                                            ushort_t* __restrict__ dst,
                                                            int Nc) {
  __shared__ float tile[32][33];
  int tx = threadIdx.x, ty = threadIdx.y;
  int c0 = blockIdx.x * 32, r0 = blockIdx.y * 32;
#pragma unroll
  for (int i = 0; i < 4; i++)
    tile[ty + i * 8][tx] = src[(size_t)(r0 + ty + i * 8) * Nc + c0 + tx];
  __syncthreads();
#pragma unroll
  for (int i = 0; i < 4; i++)
    dst[(size_t)(c0 + ty + i * 8) * KD + r0 + tx] = f2bf(tile[tx][ty + i * 8]);
}

// ---------------- v [b][g][t][d] -> vt [b][g][d][t] ----------------
__global__ __launch_bounds__(256) void vtrans_kernel(const ushort_t* __restrict__ v,
                                                     ushort_t* __restrict__ vt) {
  __shared__ ushort_t tile[64][72];
  const int bg = blockIdx.y;
  const int t0 = blockIdx.x * 64;
  const ushort_t* src = v + ((size_t)bg * TT + t0) * 64;
#pragma unroll
  for (int i = 0; i < 2; ++i) {
    int p = i * 256 + threadIdx.x;
    int r = p >> 3, c = (p & 7) * 8;
    *(short8*)&tile[r][c] = *(const short8*)(src + r * 64 + c);
  }
  __syncthreads();
  ushort_t* dst = vt + (size_t)bg * 64 * TT + t0;
#pragma unroll
  for (int i = 0; i < 2; ++i) {
    int p = i * 256 + threadIdx.x;
    int d = p >> 3, c = (p & 7) * 8;
    short8 o;
#pragma unroll
    for (int j = 0; j < 8; ++j) o[j] = tile[c + j][d];
    *(short8*)(dst + (size_t)d * TT + c) = o;
  }
}

// ---------------- GEMM, m201-style 4-phase/K-tile schedule ------------------
// BM x 256 tile, BK=64, 512 threads = 8 waves (2M x 4N). Double-buffered LDS.
// Per group (K-tile k, buf=k&1), phase q=0..3:
//   q0: ds_read B(all 8) + A-quarter0; stage Ah0(k+1)->buf^1
//   q1: ds_read A-q1;                  stage Ah1(k+1)->buf^1
//   q2: ds_read A-q2;                  stage Bh0(k+2)->buf   (B only read @q0)
//   q3: ds_read A-q3;                  stage Bh1(k+2)->buf
//   each phase: barrier; setprio(1); MFMA quarter; setprio(0); [q3: vmcnt(4)] barrier
// vmcnt(4) leaves exactly B(k+2)'s 4 loads in flight (never drains in-loop).
template <int MODE, int BM>
__global__ __launch_bounds__(512, 2) void gemm8p_kernel(
    const ushort_t* __restrict__ A, const ushort_t* __restrict__ Bt,
    const float* __restrict__ cosT, const float* __restrict__ sinT,
    ushort_t* __restrict__ q_ws, ushort_t* __restrict__ k_ws,
    ushort_t* __restrict__ v_ws, float* __restrict__ kcache,
    float* __restrict__ vcache, float* __restrict__ outF) {
  constexpr int NT = KD / 64;
  constexpr int AH = BM / 2;                  // rows per A-half
  constexpr int AL = (AH * 64) / (512 * 8);   // gloads/thread per A-half (2|1)
  constexpr int MQ = BM / 128;                // M-frags per phase (2|1)
  constexpr int MF = BM / 32;                 // M-frags per wave (8|4)
  __shared__ ushort_t sA[2][BM * 64];
  __shared__ ushort_t sB[2][256 * 64];
  const int tid = threadIdx.x;
  const int lane = tid & 63;
  const int w = tid >> 6;
  const int wm = w >> 2, wn = w & 3;
  const int rowBase = blockIdx.y * BM;
  const int colBase = blockIdx.x * 256;

  // staging maps: chunk c -> row c>>3, phys slot c&7 holds logical (c&7)^(row&7)
  int aRO[AL], aLO[AL];
#pragma unroll
  for (int i = 0; i < AL; ++i) {
    int c = i * 512 + tid;
    int r = c >> 3, lc = (c & 7) ^ (r & 7);
    aRO[i] = r * KD + lc * 8;
    aLO[i] = (i * 512 + (tid & ~63)) * 8;
  }
  int bRO[2], bLO[2];
#pragma unroll
  for (int i = 0; i < 2; ++i) {
    int c = i * 512 + tid;
    int r = c >> 3, lc = (c & 7) ^ (r & 7);
    bRO[i] = r * KD + lc * 8;
    bLO[i] = (i * 512 + (tid & ~63)) * 8;
  }

  auto stageA = [&](int bb, int kt, int h) {
    const ushort_t* base = A + (size_t)(rowBase + h * AH) * KD + kt * 64;
#pragma unroll
    for (int i = 0; i < AL; ++i)
      gload_lds16(base + aRO[i], &sA[bb][h * AH * 64 + aLO[i]]);
  };
  auto stageB = [&](int bb, int kt, int h) {
    const ushort_t* base = Bt + (size_t)(colBase + h * 128) * KD + kt * 64;
#pragma unroll
    for (int i = 0; i < 2; ++i)
      gload_lds16(base + bRO[i], &sB[bb][h * 8192 + bLO[i]]);
  };

  f32x4 acc[MF][4];
#pragma unroll
  for (int i = 0; i < MF; i++)
#pragma unroll
    for (int j = 0; j < 4; j++) acc[i][j] = f32x4{0.f, 0.f, 0.f, 0.f};

  // prologue: tile0 (4 halves) + B(1); wait tile0 (B(1) stays in flight)
  stageA(0, 0, 0); stageA(0, 0, 1); stageB(0, 0, 0); stageB(0, 0, 1);
  stageB(1, 1, 0); stageB(1, 1, 1);
  asm volatile("s_waitcnt vmcnt(4)" ::: "memory");
  __builtin_amdgcn_s_barrier();

  auto group = [&](int k, int buf) {
    short8 bf[4][2];
#pragma unroll
    for (int q = 0; q < 4; ++q) {
      if (q == 0) {
#pragma unroll
        for (int ni = 0; ni < 4; ++ni) {
          int n = wn * 64 + ni * 16 + (lane & 15);
#pragma unroll
          for (int ks = 0; ks < 2; ++ks)
            bf[ni][ks] = *(const short8*)(&sB[buf][n * 64 +
                (((ks * 4 + (lane >> 4)) ^ (n & 7)) * 8)]);
        }
      }
      short8 af[MQ][2];
#pragma unroll
      for (int mq = 0; mq < MQ; ++mq) {
        int r = wm * AH + (q * MQ + mq) * 16 + (lane & 15);
#pragma unroll
        for (int ks = 0; ks < 2; ++ks)
          af[mq][ks] = *(const short8*)(&sA[buf][r * 64 +
              (((ks * 4 + (lane >> 4)) ^ (r & 7)) * 8)]);
      }
      if (q == 0 && k + 1 < NT) stageA(buf ^ 1, k + 1, 0);
      if (q == 1 && k + 1 < NT) stageA(buf ^ 1, k + 1, 1);
      if (q == 2 && k + 2 < NT) stageB(buf, k + 2, 0);
      if (q == 3 && k + 2 < NT) stageB(buf, k + 2, 1);
      __builtin_amdgcn_s_barrier();
      __builtin_amdgcn_s_setprio(1);
#pragma unroll
      for (int mq = 0; mq < MQ; ++mq)
#pragma unroll
        for (int ni = 0; ni < 4; ++ni)
#pragma unroll
          for (int ks = 0; ks < 2; ++ks)
            acc[q * MQ + mq][ni] = __builtin_amdgcn_mfma_f32_16x16x32_bf16(
                af[mq][ks], bf[ni][ks], acc[q * MQ + mq][ni], 0, 0, 0);
      __builtin_amdgcn_s_setprio(0);
      if (q == 3) {
        if (k + 2 < NT)
          asm volatile("s_waitcnt vmcnt(4)" ::: "memory");
        else
          asm volatile("s_waitcnt vmcnt(0)" ::: "memory");
      }
      __builtin_amdgcn_s_barrier();
    }
  };

  for (int kk = 0; kk < NT; kk += 2) {
    group(kk, 0);
    group(kk + 1, 1);
  }

  // ---- epilogue: C/D layout col=lane&15, row=(lane>>4)*4+j ----
#pragma unroll
  for (int mi = 0; mi < MF; ++mi)
#pragma unroll
    for (int ni = 0; ni < 4; ++ni) {
      int cg = colBase + wn * 64 + ni * 16 + (lane & 15);
      int rg0 = rowBase + wm * AH + mi * 16 + ((lane >> 4) * 4);
      f32x4 v4 = acc[mi][ni];
#pragma unroll
      for (int j = 0; j < 4; ++j) {
        float v = v4[j];
        float pv = __shfl_xor(v, 1);
        int row = rg0 + j;
        if constexpr (MODE == 0) {
          int bb = row >> 11, tq = row & (TT - 1);
          int d = cg & 63, i2 = d >> 1;
          if (cg < 2048) {  // q (scale folds 1/8 and log2(e) for exp2 softmax)
            float cc = cosT[tq * 32 + i2], ss = sinT[tq * 32 + i2];
            float out = (d & 1) ? (pv * ss + v * cc) : (v * cc - pv * ss);
            int hh = cg >> 6;
            q_ws[(((size_t)(bb * NH + hh)) * TT + tq) * 64 + d] = f2bf(out * 0.18033688f);
          } else if (cg < 2560) {  // k (roped)
            float cc = cosT[tq * 32 + i2], ss = sinT[tq * 32 + i2];
            float out = (d & 1) ? (pv * ss + v * cc) : (v * cc - pv * ss);
            int gg = (cg - 2048) >> 6;
            kcache[(((size_t)(bb * TT + tq)) * NG + gg) * 64 + d] = out;
            k_ws[(((size_t)(bb * NG + gg)) * TT + tq) * 64 + d] = f2bf(out);
          } else {  // v (row-major; vtrans builds vt)
            int gg = (cg - 2560) >> 6;
            vcache[(((size_t)(bb * TT + tq)) * NG + gg) * 64 + d] = v;
            v_ws[(((size_t)(bb * NG + gg)) * TT + tq) * 64 + d] = f2bf(v);
          }
        } else {
          outF[(size_t)row * 2048 + cg] = v;
        }
      }
    }
}

// ---------------- flash attention: swapped 32x32 MFMA, in-register softmax
#define PACK(SV, E, OUT)                                        \
  {                                                             \
    uint32_t A0 = cvtpk(SV[8 * E + 0], SV[8 * E + 1]);          \
    uint32_t A1 = cvtpk(SV[8 * E + 2], SV[8 * E + 3]);          \
    uint32_t B0 = cvtpk(SV[8 * E + 4], SV[8 * E + 5]);          \
    uint32_t B1 = cvtpk(SV[8 * E + 6], SV[8 * E + 7]);          \
    asm("v_permlane32_swap_b32 %0, %1" : "+v"(A0), "+v"(B0));   \
    asm("v_permlane32_swap_b32 %0, %1" : "+v"(A1), "+v"(B1));   \
    union { uint32_t u[4]; short8 s8; } UU;                     \
    UU.u[0] = A0; UU.u[1] = A1; UU.u[2] = B0; UU.u[3] = B1;     \
    OUT = UU.s8;                                                \
  }

__global__ __launch_bounds__(256, 4) void attn_kernel(const ushort_t* __restrict__ qw,
                                                      const ushort_t* __restrict__ kw,
                                                      const ushort_t* __restrict__ vtw,
                                                      ushort_t* __restrict__ attn) {
  __shared__ ushort_t sK[2][4096];   // [64 keys][64 d], chunk-swizzled
  __shared__ ushort_t sVT[2][4096];  // [64 d][64 keys], chunk-swizzled
  const int tid = threadIdx.x;
  const int lane = tid & 63;
  const int w = tid >> 6;
  const int hi = lane >> 5;
  const int col = lane & 31;
  const int bid = blockIdx.x;
  const int jj = bid & 63;
  const int rep = jj >> 4;
  const int bg = jj & 15;
  const int b = bg >> 3, g = bg & 7;
  const int h = g * 4 + rep;
  const int qt = 15 - (bid >> 6);
  const int q0w = qt * 128 + w * 32;
  const int qg = q0w + col;
  const int ntiles = 2 * qt + 2;

  const ushort_t* qbase = qw + ((size_t)(b * NH + h) * TT + qg) * 64;
  const ushort_t* kbase = kw + (size_t)(b * NG + g) * TT * 64;
  const ushort_t* vtbase = vtw + (size_t)(b * NG + g) * 64 * TT;

  short8 qf[4];
#pragma unroll
  for (int dsub = 0; dsub < 4; ++dsub)
    qf[dsub] = *(const short8*)(qbase + dsub * 16 + hi * 8);

  const int r0 = tid >> 3;
  const int cl = (tid & 7) ^ (r0 & 7);
  const ushort_t* kS0 = kbase + r0 * 64 + cl * 8;
  const ushort_t* kS1 = kbase + (r0 + 32) * 64 + cl * 8;
  const ushort_t* vS0 = vtbase + (size_t)r0 * TT + cl * 8;
  const ushort_t* vS1 = vtbase + (size_t)(r0 + 32) * TT + cl * 8;
  const int off0 = (tid & ~63) * 8;
  const int off1 = off0 + 2048;

  auto stage = [&](int bb, int k0) {
    gload_lds16(kS0 + (size_t)k0 * 64, &sK[bb][off0]);
    gload_lds16(kS1 + (size_t)k0 * 64, &sK[bb][off1]);
    gload_lds16(vS0 + k0, &sVT[bb][off0]);
    gload_lds16(vS1 + k0, &sVT[bb][off1]);
  };

  f32x16 o0 = {};
  f32x16 o1 = {};
  float m_run = -3.0e38f, l_run = 0.f;

  stage(0, 0);
  asm volatile("s_waitcnt vmcnt(0)" ::: "memory");
  __syncthreads();

  for (int kt = 0; kt < ntiles; ++kt) {
    const int k0 = kt * 64;
    const int buf = kt & 1;
    if (kt + 1 < ntiles) stage(buf ^ 1, k0 + 64);
    if (k0 <= q0w + 31) {
      const ushort_t* K = sK[buf];
      const ushort_t* V = sVT[buf];
      f32x16 s0 = {};
      f32x16 s1 = {};
#pragma unroll
      for (int dsub = 0; dsub < 4; ++dsub) {
        const int ch = dsub * 2 + hi;
        const int sw = ((ch ^ (col & 7)) * 8);
        short8 a0 = *(const short8*)(K + col * 64 + sw);
        short8 a1 = *(const short8*)(K + (32 + col) * 64 + sw);
        s0 = __builtin_amdgcn_mfma_f32_32x32x16_bf16(a0, qf[dsub], s0, 0, 0, 0);
        s1 = __builtin_amdgcn_mfma_f32_32x32x16_bf16(a1, qf[dsub], s1, 0, 0, 0);
      }
      if (k0 + 63 > q0w) {
#pragma unroll
        for (int r = 0; r < 16; ++r) {
          int key5 = (r & 3) + 8 * (r >> 2) + 4 * hi;
          if (k0 + key5 > qg) s0[r] = -3.0e38f;
          if (k0 + 32 + key5 > qg) s1[r] = -3.0e38f;
        }
      }
      float tm[16];
#pragma unroll
      for (int r = 0; r < 16; ++r) tm[r] = fmaxf(s0[r], s1[r]);
#pragma unroll
      for (int st = 8; st > 0; st >>= 1)
#pragma unroll
        for (int r = 0; r < 8; ++r)
          if (r < st) tm[r] = fmaxf(tm[r], tm[r + st]);
      float mt = fmaxf(tm[0], __shfl_xor(tm[0], 32));
      float mn = fmaxf(m_run, mt);
      float al = exp2fast(m_run - mn);
      m_run = mn;
      float ts[16];
#pragma unroll
      for (int r = 0; r < 16; ++r) {
        s0[r] = exp2fast(s0[r] - mn);
        s1[r] = exp2fast(s1[r] - mn);
        ts[r] = s0[r] + s1[r];
      }
#pragma unroll
      for (int st = 8; st > 0; st >>= 1)
#pragma unroll
        for (int r = 0; r < 8; ++r)
          if (r < st) ts[r] += ts[r + st];
      float rs = ts[0] + __shfl_xor(ts[0], 32);
      l_run = l_run * al + rs;
#pragma unroll
      for (int r = 0; r < 16; ++r) { o0[r] *= al; o1[r] *= al; }
      short8 pb;
      const int swz = (col & 7);
#define PVMM(KS)                                                            \
  {                                                                         \
    const int ch = KS * 2 + hi;                                             \
    const int so = ((ch ^ swz) * 8);                                        \
    short8 va = *(const short8*)(V + col * 64 + so);                        \
    short8 vb = *(const short8*)(V + (32 + col) * 64 + so);                 \
    o0 = __builtin_amdgcn_mfma_f32_32x32x16_bf16(va, pb, o0, 0, 0, 0);      \
    o1 = __builtin_amdgcn_mfma_f32_32x32x16_bf16(vb, pb, o1, 0, 0, 0);      \
  }
      PACK(s0, 0, pb); PVMM(0)
      PACK(s0, 1, pb); PVMM(1)
      PACK(s1, 0, pb); PVMM(2)
      PACK(s1, 1, pb); PVMM(3)
#undef PVMM
    }
    asm volatile("s_waitcnt vmcnt(0)" ::: "memory");
    __syncthreads();
  }

  const float inv = 1.f / l_run;
  ushort_t* obase = attn + ((size_t)b * TT + qg) * 2048 + h * 64;
#pragma unroll
  for (int g4 = 0; g4 < 4; ++g4) {
    int d = g4 * 8 + hi * 4;
    uint2v u;
    u[0] = cvtpk(o0[4 * g4 + 0] * inv, o0[4 * g4 + 1] * inv);
    u[1] = cvtpk(o0[4 * g4 + 2] * inv, o0[4 * g4 + 3] * inv);
    *(uint2v*)(obase + d) = u;
    uint2v u2;
    u2[0] = cvtpk(o1[4 * g4 + 0] * inv, o1[4 * g4 + 1] * inv);
    u2[1] = cvtpk(o1[4 * g4 + 2] * inv, o1[4 * g4 + 3] * inv);
    *(uint2v*)(obase + 32 + d) = u2;
  }
}

extern "C" void kernel_launch(void* const* d_in, const int* in_sizes, int n_in,
                              void* d_out, int out_size, void* d_ws, size_t ws_size,
                              hipStream_t stream) {
  (void)in_sizes; (void)n_in; (void)out_size; (void)ws_size;
  const float* x    = (const float*)d_in[0];
  const float* cosT = (const float*)d_in[1];
  const float* sinT = (const float*)d_in[2];
  const float* Wq   = (const float*)d_in[4];
  const float* Wk   = (const float*)d_in[5];
  const float* Wv   = (const float*)d_in[6];
  const float* Wo   = (const float*)d_in[7];

  float* outF   = (float*)d_out;
  float* kcache = outF + (size_t)8388608;             // B*T*C
  float* vcache = kcache + (size_t)2097152;           // B*T*G*D

  uint8_t* ws = (uint8_t*)d_ws;
  ushort_t* x_bf   = (ushort_t*)(ws);
  ushort_t* wqkvT  = (ushort_t*)(ws + 16777216);
  ushort_t* vt_ws  = (ushort_t*)(ws + 16777216);      // overlays wqkvT (dead)
  ushort_t* q_ws   = (ushort_t*)(ws + 29360128);
  ushort_t* k_ws   = (ushort_t*)(ws + 46137344);
  ushort_t* v_ws   = (ushort_t*)(ws + 50331648);
  ushort_t* woT    = (ushort_t*)(ws + 54525952);
  ushort_t* attn_ws= (ushort_t*)(ws + 62914560);

  cvt_x_kernel<<<8192, 256, 0, stream>>>(x, x_bf);
  cvt_transpose_kernel<<<dim3(64, 64), dim3(32, 8), 0, stream>>>(Wq, wqkvT, 2048);
  cvt_transpose_kernel<<<dim3(16, 64), dim3(32, 8), 0, stream>>>(Wk, wqkvT + (size_t)2048 * KD, 512);
  cvt_transpose_kernel<<<dim3(16, 64), dim3(32, 8), 0, stream>>>(Wv, wqkvT + (size_t)2560 * KD, 512);
  cvt_transpose_kernel<<<dim3(64, 64), dim3(32, 8), 0, stream>>>(Wo, woT, 2048);

  gemm8p_kernel<0, 256><<<dim3(12, 16), 512, 0, stream>>>(x_bf, wqkvT, cosT, sinT,
                                                          q_ws, k_ws, v_ws, kcache,
                                                          vcache, nullptr);
  vtrans_kernel<<<dim3(32, 16), 256, 0, stream>>>(v_ws, vt_ws);
  attn_kernel<<<1024, 256, 0, stream>>>(q_ws, k_ws, vt_ws, attn_ws);
  gemm8p_kernel<1, 128><<<dim3(8, 32), 512, 0, stream>>>(attn_ws, woT, nullptr, nullptr,
                                                         nullptr, nullptr, nullptr,
                                                         nullptr, nullptr, outF);
}

// Round 7
// 200.895 us; speedup vs baseline: 1.2489x; 1.0914x over previous
//
#include <hip/hip_runtime.h>
#include <cstdint>
#include <cstddef>

typedef unsigned short ushort_t;
typedef __attribute__((ext_vector_type(4))) float f32x4;
typedef __attribute__((ext_vector_type(16))) float f32x16;
typedef __attribute__((ext_vector_type(8))) short short8;
typedef __attribute__((ext_vector_type(4))) float float4_t;
typedef __attribute__((ext_vector_type(4))) unsigned short ushort4_t;
typedef __attribute__((ext_vector_type(2))) unsigned int uint2v;

#define KD 2048     // inner dim of both GEMMs
#define TT 2048     // sequence length T
#define NH 32       // heads
#define NG 8        // kv groups

__device__ __forceinline__ ushort_t f2bf(float f) {
  union { float f; uint32_t u; } cv; cv.f = f;
  uint32_t u = cv.u;
  return (ushort_t)((u + 0x7FFFu + ((u >> 16) & 1u)) >> 16);
}

__device__ __forceinline__ uint32_t cvtpk(float a, float b) {
  uint32_t r;
  asm("v_cvt_pk_bf16_f32 %0, %1, %2" : "=v"(r) : "v"(a), "v"(b));
  return r;
}

__device__ __forceinline__ float exp2fast(float x) {
  float r;
  asm("v_exp_f32 %0, %1" : "=v"(r) : "v"(x));
  return r;
}

__device__ __forceinline__ void gload_lds16(const void* g, void* l) {
  __builtin_amdgcn_global_load_lds(
      (const __attribute__((address_space(1))) unsigned int*)g,
      (__attribute__((address_space(3))) unsigned int*)l, 16, 0, 0);
}

// ---------------- x f32 -> bf16 ----------------
__global__ __launch_bounds__(256) void cvt_x_kernel(const float* __restrict__ src,
                                                    ushort_t* __restrict__ dst) {
  int i = (blockIdx.x * 256 + threadIdx.x) * 4;
  float4_t v = *(const float4_t*)(src + i);
  ushort4_t o;
  o[0] = f2bf(v[0]); o[1] = f2bf(v[1]); o[2] = f2bf(v[2]); o[3] = f2bf(v[3]);
  *(ushort4_t*)(dst + i) = o;
}

// ---------------- W f32 [K][Nc] -> bf16 [Nc][K] (transposed) ----------------
__global__ __launch_bounds__(256) void cvt_transpose_kernel(const float* __restrict__ src,
                                                            ushort_t* __restrict__ dst,
                                                            int Nc) {
  __shared__ float tile[32][33];
  int tx = threadIdx.x, ty = threadIdx.y;
  int c0 = blockIdx.x * 32, r0 = blockIdx.y * 32;
#pragma unroll
  for (int i = 0; i < 4; i++)
    tile[ty + i * 8][tx] = src[(size_t)(r0 + ty + i * 8) * Nc + c0 + tx];
  __syncthreads();
#pragma unroll
  for (int i = 0; i < 4; i++)
    dst[(size_t)(c0 + ty + i * 8) * KD + r0 + tx] = f2bf(tile[tx][ty + i * 8]);
}

// ---------------- v [b][g][t][d] -> vt [b][g][d][t] ----------------
__global__ __launch_bounds__(256) void vtrans_kernel(const ushort_t* __restrict__ v,
                                                     ushort_t* __restrict__ vt) {
  __shared__ ushort_t tile[64][72];
  const int bg = blockIdx.y;
  const int t0 = blockIdx.x * 64;
  const ushort_t* src = v + ((size_t)bg * TT + t0) * 64;
#pragma unroll
  for (int i = 0; i < 2; ++i) {
    int p = i * 256 + threadIdx.x;
    int r = p >> 3, c = (p & 7) * 8;
    *(short8*)&tile[r][c] = *(const short8*)(src + r * 64 + c);
  }
  __syncthreads();
  ushort_t* dst = vt + (size_t)bg * 64 * TT + t0;
#pragma unroll
  for (int i = 0; i < 2; ++i) {
    int p = i * 256 + threadIdx.x;
    int d = p >> 3, c = (p & 7) * 8;
    short8 o;
#pragma unroll
    for (int j = 0; j < 8; ++j) o[j] = tile[c + j][d];
    *(short8*)(dst + (size_t)d * TT + c) = o;
  }
}

// ------------- GEMM, 2-fat-phase/K-tile, tri-buffered A, dbuf B -------------
// BM=256 x BN tile, BK=64, 512 threads = 8 waves (WM x WN grid).
// Per K-tile k (A slot k%3, B buf k&1), two phases:
//   q0: ds_read B-frags(all) + A-frags half0; stage A(k+2)->slot (k+2)%3
//       barrier; MFMA half0; barrier
//   q1: ds_read A-frags half1;               stage B(k+2)->buf k&1
//       barrier; MFMA half1; vmcnt(4+BL) [last 2 tiles: vmcnt(0)]; barrier
// vmcnt(4+BL) leaves exactly this group's A(k+2)+B(k+2) in flight, forcing
// everything older (incl. A(k+1), B(k+1)) landed. Lead distance = 2 K-tiles.
template <int MODE, int BN, int WM>
__global__ __launch_bounds__(512) void gemmf_kernel(
    const ushort_t* __restrict__ A, const ushort_t* __restrict__ Bt,
    const float* __restrict__ cosT, const float* __restrict__ sinT,
    ushort_t* __restrict__ q_ws, ushort_t* __restrict__ k_ws,
    ushort_t* __restrict__ v_ws, float* __restrict__ kcache,
    float* __restrict__ vcache, float* __restrict__ outF) {
  constexpr int NT = KD / 64;
  constexpr int WN = 8 / WM;
  constexpr int RW = 256 / WM;      // rows per wave
  constexpr int CW = BN / WN;       // cols per wave
  constexpr int MF = RW / 16;       // A-frags per wave
  constexpr int NF = CW / 16;       // B-frags per wave
  constexpr int MQ = MF / 2;        // A-frags per phase
  constexpr int BL = BN / 64;       // B gload insts per K-tile (3 or 2)
  constexpr int ASZ = 256 * 64;     // elems per A slot
  constexpr int BSZ = BN * 64;
  __shared__ ushort_t sA[3 * ASZ];
  __shared__ ushort_t sB[2 * BSZ];
  const int tid = threadIdx.x;
  const int lane = tid & 63;
  const int w = tid >> 6;
  const int wm = (WM == 2) ? (w >> 2) : (w >> 1);
  const int wn = (WM == 2) ? (w & 3) : (w & 1);
  const int rowBase = blockIdx.y * 256;
  const int colBase = blockIdx.x * BN;

  // staging maps: chunk c -> row c>>3; phys slot c&7 holds logical (c&7)^(row&7)
  int aRO[4], aLO[4];
#pragma unroll
  for (int i = 0; i < 4; ++i) {
    int c = i * 512 + tid;
    int r = c >> 3, lc = (c & 7) ^ (r & 7);
    aRO[i] = r * KD + lc * 8;
    aLO[i] = (i * 512 + (tid & ~63)) * 8;
  }
  int bRO[BL], bLO[BL];
#pragma unroll
  for (int i = 0; i < BL; ++i) {
    int c = i * 512 + tid;
    int r = c >> 3, lc = (c & 7) ^ (r & 7);
    bRO[i] = r * KD + lc * 8;
    bLO[i] = (i * 512 + (tid & ~63)) * 8;
  }

  auto stageA = [&](int slot, int kt) {
    const ushort_t* base = A + (size_t)rowBase * KD + kt * 64;
#pragma unroll
    for (int i = 0; i < 4; ++i)
      gload_lds16(base + aRO[i], &sA[slot * ASZ + aLO[i]]);
  };
  auto stageB = [&](int bb, int kt) {
    const ushort_t* base = Bt + (size_t)colBase * KD + kt * 64;
#pragma unroll
    for (int i = 0; i < BL; ++i)
      gload_lds16(base + bRO[i], &sB[bb * BSZ + bLO[i]]);
  };

  f32x4 acc[MF][NF];
#pragma unroll
  for (int i = 0; i < MF; i++)
#pragma unroll
    for (int j = 0; j < NF; j++) acc[i][j] = f32x4{0.f, 0.f, 0.f, 0.f};

  // prologue: tiles 0,1 staged; wait tile0 (tile1 in flight)
  stageA(0, 0); stageB(0, 0);
  stageA(1, 1); stageB(1, 1);
  asm volatile("s_waitcnt vmcnt(%0)" :: "n"(4 + BL) : "memory");
  __builtin_amdgcn_s_barrier();

  int am3 = 0;   // k % 3
  int sm3 = 2;   // (k+2) % 3
  for (int k = 0; k < NT; ++k) {
    const int bb = k & 1;
    const ushort_t* Abuf = &sA[am3 * ASZ];
    const ushort_t* Bbuf = &sB[bb * BSZ];

    // ---------------- q0 ----------------
    short8 bfr[NF][2];
#pragma unroll
    for (int ni = 0; ni < NF; ++ni) {
      int n = wn * CW + ni * 16 + (lane & 15);
#pragma unroll
      for (int ks = 0; ks < 2; ++ks)
        bfr[ni][ks] = *(const short8*)(&Bbuf[n * 64 +
            (((ks * 4 + (lane >> 4)) ^ (n & 7)) * 8)]);
    }
    short8 af0[MQ][2];
#pragma unroll
    for (int mq = 0; mq < MQ; ++mq) {
      int r = wm * RW + mq * 16 + (lane & 15);
#pragma unroll
      for (int ks = 0; ks < 2; ++ks)
        af0[mq][ks] = *(const short8*)(&Abuf[r * 64 +
            (((ks * 4 + (lane >> 4)) ^ (r & 7)) * 8)]);
    }
    if (k + 2 < NT) stageA(sm3, k + 2);
    __builtin_amdgcn_s_barrier();
    __builtin_amdgcn_s_setprio(1);
#pragma unroll
    for (int ks = 0; ks < 2; ++ks)
#pragma unroll
      for (int mq = 0; mq < MQ; ++mq)
#pragma unroll
        for (int ni = 0; ni < NF; ++ni)
          acc[mq][ni] = __builtin_amdgcn_mfma_f32_16x16x32_bf16(
              af0[mq][ks], bfr[ni][ks], acc[mq][ni], 0, 0, 0);
    __builtin_amdgcn_s_setprio(0);
    __builtin_amdgcn_s_barrier();

    // ---------------- q1 ----------------
    short8 af1[MQ][2];
#pragma unroll
    for (int mq = 0; mq < MQ; ++mq) {
      int r = wm * RW + (MQ + mq) * 16 + (lane & 15);
#pragma unroll
      for (int ks = 0; ks < 2; ++ks)
        af1[mq][ks] = *(const short8*)(&Abuf[r * 64 +
            (((ks * 4 + (lane >> 4)) ^ (r & 7)) * 8)]);
    }
    if (k + 2 < NT) stageB(bb, k + 2);
    __builtin_amdgcn_s_barrier();
    __builtin_amdgcn_s_setprio(1);
#pragma unroll
    for (int ks = 0; ks < 2; ++ks)
#pragma unroll
      for (int mq = 0; mq < MQ; ++mq)
#pragma unroll
        for (int ni = 0; ni < NF; ++ni)
          acc[MQ + mq][ni] = __builtin_amdgcn_mfma_f32_16x16x32_bf16(
              af1[mq][ks], bfr[ni][ks], acc[MQ + mq][ni], 0, 0, 0);
    __builtin_amdgcn_s_setprio(0);
    if (k + 2 < NT)
      asm volatile("s_waitcnt vmcnt(%0)" :: "n"(4 + BL) : "memory");
    else
      asm volatile("s_waitcnt vmcnt(0)" ::: "memory");
    __builtin_amdgcn_s_barrier();

    am3 = (am3 == 2) ? 0 : am3 + 1;
    sm3 = (sm3 == 2) ? 0 : sm3 + 1;
  }

  // ---- epilogue: C/D layout col=lane&15, row=(lane>>4)*4+j ----
#pragma unroll
  for (int mi = 0; mi < MF; ++mi)
#pragma unroll
    for (int ni = 0; ni < NF; ++ni) {
      int cg = colBase + wn * CW + ni * 16 + (lane & 15);
      int rg0 = rowBase + wm * RW + mi * 16 + ((lane >> 4) * 4);
      f32x4 v4 = acc[mi][ni];
#pragma unroll
      for (int j = 0; j < 4; ++j) {
        float v = v4[j];
        float pv = __shfl_xor(v, 1);
        int row = rg0 + j;
        if constexpr (MODE == 0) {
          int bb = row >> 11, tq = row & (TT - 1);
          int d = cg & 63, i2 = d >> 1;
          if (cg < 2048) {  // q (scale folds 1/8 and log2(e) for exp2 softmax)
            float cc = cosT[tq * 32 + i2], ss = sinT[tq * 32 + i2];
            float out = (d & 1) ? (pv * ss + v * cc) : (v * cc - pv * ss);
            int hh = cg >> 6;
            q_ws[(((size_t)(bb * NH + hh)) * TT + tq) * 64 + d] = f2bf(out * 0.18033688f);
          } else if (cg < 2560) {  // k (roped)
            float cc = cosT[tq * 32 + i2], ss = sinT[tq * 32 + i2];
            float out = (d & 1) ? (pv * ss + v * cc) : (v * cc - pv * ss);
            int gg = (cg - 2048) >> 6;
            kcache[(((size_t)(bb * TT + tq)) * NG + gg) * 64 + d] = out;
            k_ws[(((size_t)(bb * NG + gg)) * TT + tq) * 64 + d] = f2bf(out);
          } else {  // v (row-major; vtrans builds vt)
            int gg = (cg - 2560) >> 6;
            vcache[(((size_t)(bb * TT + tq)) * NG + gg) * 64 + d] = v;
            v_ws[(((size_t)(bb * NG + gg)) * TT + tq) * 64 + d] = f2bf(v);
          }
        } else {
          outF[(size_t)row * 2048 + cg] = v;
        }
      }
    }
}

// ---------------- flash attention: swapped 32x32 MFMA, in-register softmax
#define PACK(SV, E, OUT)                                        \
  {                                                             \
    uint32_t A0 = cvtpk(SV[8 * E + 0], SV[8 * E + 1]);          \
    uint32_t A1 = cvtpk(SV[8 * E + 2], SV[8 * E + 3]);          \
    uint32_t B0 = cvtpk(SV[8 * E + 4], SV[8 * E + 5]);          \
    uint32_t B1 = cvtpk(SV[8 * E + 6], SV[8 * E + 7]);          \
    asm("v_permlane32_swap_b32 %0, %1" : "+v"(A0), "+v"(B0));   \
    asm("v_permlane32_swap_b32 %0, %1" : "+v"(A1), "+v"(B1));   \
    union { uint32_t u[4]; short8 s8; } UU;                     \
    UU.u[0] = A0; UU.u[1] = A1; UU.u[2] = B0; UU.u[3] = B1;     \
    OUT = UU.s8;                                                \
  }

__global__ __launch_bounds__(256, 4) void attn_kernel(const ushort_t* __restrict__ qw,
                                                      const ushort_t* __restrict__ kw,
                                                      const ushort_t* __restrict__ vtw,
                                                      ushort_t* __restrict__ attn) {
  __shared__ ushort_t sK[2][4096];   // [64 keys][64 d], chunk-swizzled
  __shared__ ushort_t sVT[2][4096];  // [64 d][64 keys], chunk-swizzled
  const int tid = threadIdx.x;
  const int lane = tid & 63;
  const int w = tid >> 6;
  const int hi = lane >> 5;
  const int col = lane & 31;
  const int bid = blockIdx.x;
  const int jj = bid & 63;
  const int rep = jj >> 4;
  const int bg = jj & 15;
  const int b = bg >> 3, g = bg & 7;
  const int h = g * 4 + rep;
  const int qt = 15 - (bid >> 6);
  const int q0w = qt * 128 + w * 32;
  const int qg = q0w + col;
  const int ntiles = 2 * qt + 2;

  const ushort_t* qbase = qw + ((size_t)(b * NH + h) * TT + qg) * 64;
  const ushort_t* kbase = kw + (size_t)(b * NG + g) * TT * 64;
  const ushort_t* vtbase = vtw + (size_t)(b * NG + g) * 64 * TT;

  short8 qf[4];
#pragma unroll
  for (int dsub = 0; dsub < 4; ++dsub)
    qf[dsub] = *(const short8*)(qbase + dsub * 16 + hi * 8);

  const int r0 = tid >> 3;
  const int cl = (tid & 7) ^ (r0 & 7);
  const ushort_t* kS0 = kbase + r0 * 64 + cl * 8;
  const ushort_t* kS1 = kbase + (r0 + 32) * 64 + cl * 8;
  const ushort_t* vS0 = vtbase + (size_t)r0 * TT + cl * 8;
  const ushort_t* vS1 = vtbase + (size_t)(r0 + 32) * TT + cl * 8;
  const int off0 = (tid & ~63) * 8;
  const int off1 = off0 + 2048;

  auto stage = [&](int bb, int k0) {
    gload_lds16(kS0 + (size_t)k0 * 64, &sK[bb][off0]);
    gload_lds16(kS1 + (size_t)k0 * 64, &sK[bb][off1]);
    gload_lds16(vS0 + k0, &sVT[bb][off0]);
    gload_lds16(vS1 + k0, &sVT[bb][off1]);
  };

  f32x16 o0 = {};
  f32x16 o1 = {};
  float m_run = -3.0e38f, l_run = 0.f;

  stage(0, 0);
  asm volatile("s_waitcnt vmcnt(0)" ::: "memory");
  __syncthreads();

  for (int kt = 0; kt < ntiles; ++kt) {
    const int k0 = kt * 64;
    const int buf = kt & 1;
    if (kt + 1 < ntiles) stage(buf ^ 1, k0 + 64);
    if (k0 <= q0w + 31) {
      const ushort_t* K = sK[buf];
      const ushort_t* V = sVT[buf];
      f32x16 s0 = {};
      f32x16 s1 = {};
#pragma unroll
      for (int dsub = 0; dsub < 4; ++dsub) {
        const int ch = dsub * 2 + hi;
        const int sw = ((ch ^ (col & 7)) * 8);
        short8 a0 = *(const short8*)(K + col * 64 + sw);
        short8 a1 = *(const short8*)(K + (32 + col) * 64 + sw);
        s0 = __builtin_amdgcn_mfma_f32_32x32x16_bf16(a0, qf[dsub], s0, 0, 0, 0);
        s1 = __builtin_amdgcn_mfma_f32_32x32x16_bf16(a1, qf[dsub], s1, 0, 0, 0);
      }
      if (k0 + 63 > q0w) {
#pragma unroll
        for (int r = 0; r < 16; ++r) {
          int key5 = (r & 3) + 8 * (r >> 2) + 4 * hi;
          if (k0 + key5 > qg) s0[r] = -3.0e38f;
          if (k0 + 32 + key5 > qg) s1[r] = -3.0e38f;
        }
      }
      float tm[16];
#pragma unroll
      for (int r = 0; r < 16; ++r) tm[r] = fmaxf(s0[r], s1[r]);
#pragma unroll
      for (int st = 8; st > 0; st >>= 1)
#pragma unroll
        for (int r = 0; r < 8; ++r)
          if (r < st) tm[r] = fmaxf(tm[r], tm[r + st]);
      float mt = fmaxf(tm[0], __shfl_xor(tm[0], 32));
      float mn = fmaxf(m_run, mt);
      float al = exp2fast(m_run - mn);
      m_run = mn;
      float ts[16];
#pragma unroll
      for (int r = 0; r < 16; ++r) {
        s0[r] = exp2fast(s0[r] - mn);
        s1[r] = exp2fast(s1[r] - mn);
        ts[r] = s0[r] + s1[r];
      }
#pragma unroll
      for (int st = 8; st > 0; st >>= 1)
#pragma unroll
        for (int r = 0; r < 8; ++r)
          if (r < st) ts[r] += ts[r + st];
      float rs = ts[0] + __shfl_xor(ts[0], 32);
      l_run = l_run * al + rs;
#pragma unroll
      for (int r = 0; r < 16; ++r) { o0[r] *= al; o1[r] *= al; }
      short8 pb;
      const int swz = (col & 7);
#define PVMM(KS)                                                            \
  {                                                                         \
    const int ch = KS * 2 + hi;                                             \
    const int so = ((ch ^ swz) * 8);                                        \
    short8 va = *(const short8*)(V + col * 64 + so);                        \
    short8 vb = *(const short8*)(V + (32 + col) * 64 + so);                 \
    o0 = __builtin_amdgcn_mfma_f32_32x32x16_bf16(va, pb, o0, 0, 0, 0);      \
    o1 = __builtin_amdgcn_mfma_f32_32x32x16_bf16(vb, pb, o1, 0, 0, 0);      \
  }
      PACK(s0, 0, pb); PVMM(0)
      PACK(s0, 1, pb); PVMM(1)
      PACK(s1, 0, pb); PVMM(2)
      PACK(s1, 1, pb); PVMM(3)
#undef PVMM
    }
    asm volatile("s_waitcnt vmcnt(0)" ::: "memory");
    __syncthreads();
  }

  const float inv = 1.f / l_run;
  ushort_t* obase = attn + ((size_t)b * TT + qg) * 2048 + h * 64;
#pragma unroll
  for (int g4 = 0; g4 < 4; ++g4) {
    int d = g4 * 8 + hi * 4;
    uint2v u;
    u[0] = cvtpk(o0[4 * g4 + 0] * inv, o0[4 * g4 + 1] * inv);
    u[1] = cvtpk(o0[4 * g4 + 2] * inv, o0[4 * g4 + 3] * inv);
    *(uint2v*)(obase + d) = u;
    uint2v u2;
    u2[0] = cvtpk(o1[4 * g4 + 0] * inv, o1[4 * g4 + 1] * inv);
    u2[1] = cvtpk(o1[4 * g4 + 2] * inv, o1[4 * g4 + 3] * inv);
    *(uint2v*)(obase + 32 + d) = u2;
  }
}

extern "C" void kernel_launch(void* const* d_in, const int* in_sizes, int n_in,
                              void* d_out, int out_size, void* d_ws, size_t ws_size,
                              hipStream_t stream) {
  (void)in_sizes; (void)n_in; (void)out_size; (void)ws_size;
  const float* x    = (const float*)d_in[0];
  const float* cosT = (const float*)d_in[1];
  const float* sinT = (const float*)d_in[2];
  const float* Wq   = (const float*)d_in[4];
  const float* Wk   = (const float*)d_in[5];
  const float* Wv   = (const float*)d_in[6];
  const float* Wo   = (const float*)d_in[7];

  float* outF   = (float*)d_out;
  float* kcache = outF + (size_t)8388608;             // B*T*C
  float* vcache = kcache + (size_t)2097152;           // B*T*G*D

  uint8_t* ws = (uint8_t*)d_ws;
  ushort_t* x_bf   = (ushort_t*)(ws);
  ushort_t* wqkvT  = (ushort_t*)(ws + 16777216);
  ushort_t* vt_ws  = (ushort_t*)(ws + 16777216);      // overlays wqkvT (dead)
  ushort_t* q_ws   = (ushort_t*)(ws + 29360128);
  ushort_t* k_ws   = (ushort_t*)(ws + 46137344);
  ushort_t* v_ws   = (ushort_t*)(ws + 50331648);
  ushort_t* woT    = (ushort_t*)(ws + 54525952);
  ushort_t* attn_ws= (ushort_t*)(ws + 62914560);

  cvt_x_kernel<<<8192, 256, 0, stream>>>(x, x_bf);
  cvt_transpose_kernel<<<dim3(64, 64), dim3(32, 8), 0, stream>>>(Wq, wqkvT, 2048);
  cvt_transpose_kernel<<<dim3(16, 64), dim3(32, 8), 0, stream>>>(Wk, wqkvT + (size_t)2048 * KD, 512);
  cvt_transpose_kernel<<<dim3(16, 64), dim3(32, 8), 0, stream>>>(Wv, wqkvT + (size_t)2560 * KD, 512);
  cvt_transpose_kernel<<<dim3(64, 64), dim3(32, 8), 0, stream>>>(Wo, woT, 2048);

  // QKV: 256x192 tile, wave grid 2x4 (per-wave 128x48), grid 16x16 = 256 blocks
  gemmf_kernel<0, 192, 2><<<dim3(16, 16), 512, 0, stream>>>(x_bf, wqkvT, cosT, sinT,
                                                            q_ws, k_ws, v_ws, kcache,
                                                            vcache, nullptr);
  vtrans_kernel<<<dim3(32, 16), 256, 0, stream>>>(v_ws, vt_ws);
  attn_kernel<<<1024, 256, 0, stream>>>(q_ws, k_ws, vt_ws, attn_ws);
  // proj: 256x128 tile, wave grid 4x2 (per-wave 64x64), grid 16x16 = 256 blocks
  gemmf_kernel<1, 128, 4><<<dim3(16, 16), 512, 0, stream>>>(attn_ws, woT, nullptr,
                                                            nullptr, nullptr, nullptr,
                                                            nullptr, nullptr, nullptr,
                                                            outF);
}